// Round 1
// baseline (219.341 us; speedup 1.0000x reference)
//
#include <hip/hip_runtime.h>

// ---------- types ----------
typedef __attribute__((ext_vector_type(8))) short bf16x8;   // 8 bf16 = 4 VGPR
typedef __attribute__((ext_vector_type(4))) float f32x4;

#define MFMA16(A, B, C) __builtin_amdgcn_mfma_f32_16x16x32_bf16((A), (B), (C), 0, 0, 0)

// fp32 -> bf16 (round-to-nearest-even), header-independent
__device__ __forceinline__ unsigned short f2b(float f) {
  unsigned u = __builtin_bit_cast(unsigned, f);
  unsigned r = (u + 0x7fffu + ((u >> 16) & 1u)) >> 16;
  return (unsigned short)r;
}

// async global->LDS, 16B per lane. dest = wave-uniform base + lane*16
__device__ __forceinline__ void gload16(const void* g, void* l) {
  __builtin_amdgcn_global_load_lds(
      (const __attribute__((address_space(1))) void*)g,
      (__attribute__((address_space(3))) void*)l, 16, 0, 0);
}

// ---------- pre-pass: fp32 -> bf16 (vectorized) ----------
__global__ void conv_bf16_kernel(const float* __restrict__ src,
                                 unsigned short* __restrict__ dst, int n) {
  int i = (blockIdx.x * blockDim.x + threadIdx.x) * 4;
  if (i < n) {
    float4 v = *(const float4*)(src + i);
    ushort4 o;
    o.x = f2b(v.x); o.y = f2b(v.y); o.z = f2b(v.z); o.w = f2b(v.w);
    *(ushort4*)(dst + i) = o;
  }
}

// ---------- pre-pass: transpose fp32 [R][C] -> bf16 [C][R] ----------
__global__ __launch_bounds__(1024) void transpose_bf16_kernel(
    const float* __restrict__ src, unsigned short* __restrict__ dst, int R, int C) {
  __shared__ unsigned short t[32][33];
  int x = threadIdx.x, y = threadIdx.y;
  int c0 = blockIdx.x * 32, r0 = blockIdx.y * 32;
  t[y][x] = f2b(src[(size_t)(r0 + y) * C + c0 + x]);
  __syncthreads();
  dst[(size_t)(c0 + y) * R + r0 + x] = t[x][y];
}

// ---------- GEMM: C[M,N] = A[M,K] * Bt[N,K]^T (+bias), bf16 MFMA ----------
// MODE 0: QKV projection epilogue (scatter q/k/v, bf16 + fp32 outputs)
// MODE 1: out projection epilogue (plain fp32 store)
template <int MODE>
__global__ __launch_bounds__(256, 2) void gemm_bf16_kernel(
    const unsigned short* __restrict__ A, const unsigned short* __restrict__ Bt,
    const float* __restrict__ bias, int M, int N, int K,
    unsigned short* __restrict__ q_bf, unsigned short* __restrict__ k_bf,
    unsigned short* __restrict__ vt_bf, float* __restrict__ k_out,
    float* __restrict__ v_out, float* __restrict__ y_out) {
  __shared__ __align__(16) unsigned short As[128 * 64];
  __shared__ __align__(16) unsigned short Bs[128 * 64];
  const int tid = threadIdx.x;
  const int lane = tid & 63, wid = tid >> 6;
  const int wr = wid >> 1, wc = wid & 1;
  const int l15 = lane & 15, lg = lane >> 4;
  const int m0 = blockIdx.y * 128, n0 = blockIdx.x * 128;

  f32x4 acc[4][4] = {};

  // staging source coords (XOR-swizzled source so swizzled reads see linear data)
  int rowS[4], colS[4];
#pragma unroll
  for (int j = 0; j < 4; ++j) {
    int L = j * 4096 + wid * 1024 + lane * 16;  // linear LDS byte
    int row = L >> 7;
    int c = (L & 127) ^ ((row & 7) << 4);
    rowS[j] = row;
    colS[j] = c >> 1;  // bf16 elements
  }

  for (int kt = 0; kt < K; kt += 64) {
    __syncthreads();
#pragma unroll
    for (int j = 0; j < 4; ++j) {
      gload16(A + (size_t)(m0 + rowS[j]) * K + kt + colS[j],
              (char*)As + j * 4096 + wid * 1024);
      gload16(Bt + (size_t)(n0 + rowS[j]) * K + kt + colS[j],
              (char*)Bs + j * 4096 + wid * 1024);
    }
    __syncthreads();

    bf16x8 af[4][2], bfr[4][2];
#pragma unroll
    for (int i = 0; i < 4; ++i)
#pragma unroll
      for (int kk = 0; kk < 2; ++kk) {
        int ra = wr * 64 + i * 16 + l15;
        int cb = kk * 64 + lg * 16;
        af[i][kk] = *(const bf16x8*)((const char*)As + ra * 128 + (cb ^ ((ra & 7) << 4)));
        int rb = wc * 64 + i * 16 + l15;
        bfr[i][kk] = *(const bf16x8*)((const char*)Bs + rb * 128 + (cb ^ ((rb & 7) << 4)));
      }
#pragma unroll
    for (int mi = 0; mi < 4; ++mi)
#pragma unroll
      for (int ni = 0; ni < 4; ++ni)
#pragma unroll
        for (int kk = 0; kk < 2; ++kk)
          acc[mi][ni] = MFMA16(af[mi][kk], bfr[ni][kk], acc[mi][ni]);
  }

  // epilogue: D mapping col = lane&15, row = (lane>>4)*4 + reg
#pragma unroll
  for (int ni = 0; ni < 4; ++ni) {
    int gn = n0 + wc * 64 + ni * 16 + l15;
    float bv = bias[gn];
    if (MODE == 0) {
      int which = gn >> 10, rem = gn & 1023;
      int h = rem >> 6, dh = rem & 63;
#pragma unroll
      for (int mi = 0; mi < 4; ++mi) {
        int gmb = m0 + wr * 64 + mi * 16 + lg * 4;
#pragma unroll
        for (int r = 0; r < 4; ++r) {
          int gm = gmb + r;
          int b = gm >> 11, t = gm & 2047;
          float val = acc[mi][ni][r] + bv;
          size_t idx = ((size_t)((b * 16 + h) * 2048 + t)) * 64 + dh;
          if (which == 0) {
            q_bf[idx] = f2b(val);
          } else if (which == 1) {
            k_out[idx] = val;
            k_bf[idx] = f2b(val);
          } else {
            v_out[idx] = val;
            vt_bf[((size_t)(b * 16 + h) * 64 + dh) * 2048 + t] = f2b(val);
          }
        }
      }
    } else {
#pragma unroll
      for (int mi = 0; mi < 4; ++mi) {
        int gmb = m0 + wr * 64 + mi * 16 + lg * 4;
#pragma unroll
        for (int r = 0; r < 4; ++r)
          y_out[(size_t)(gmb + r) * N + gn] = acc[mi][ni][r] + bv;
      }
    }
  }
}

// ---------- causal flash attention ----------
// one wave per 16 q-rows; KV tiles of 32; swapped QK^T (S^T = K*Q^T) so the
// q index is lane-local (n = lane&15) and softmax reduce is 2 shuffles.
__global__ __launch_bounds__(256) void attn_kernel(
    const unsigned short* __restrict__ qb, const unsigned short* __restrict__ kb,
    const unsigned short* __restrict__ vtb, unsigned short* __restrict__ y_att) {
  __shared__ __align__(16) unsigned short P_lds[4][16 * 48];
  const int tid = threadIdx.x, lane = tid & 63, w = tid >> 6;
  const int gw = blockIdx.x * 4 + w;
  const int qt = 127 - (gw >> 5);  // heaviest tiles first
  const int bh = gw & 31;
  const int q0 = qt * 16;
  const int l15 = lane & 15, lg = lane >> 4;
  const size_t base_off = (size_t)bh * 2048 * 64;
  const unsigned short* Q = qb + base_off;
  const unsigned short* Kp = kb + base_off;
  const unsigned short* Vt = vtb + base_off;  // [64][2048]
  unsigned short* Pl = P_lds[w];

  bf16x8 qf0 = *(const bf16x8*)(Q + (size_t)(q0 + l15) * 64 + lg * 8);
  bf16x8 qf1 = *(const bf16x8*)(Q + (size_t)(q0 + l15) * 64 + 32 + lg * 8);

  f32x4 yacc[4] = {};
  float m_run = -1e30f, l_run = 0.f;
  const int q_idx = q0 + l15;
  const float sc = 0.125f * 1.44269504f;  // 1/sqrt(64) * log2(e)

  for (int kv0 = 0; kv0 <= q0 + 15; kv0 += 32) {
    f32x4 st0 = {}, st1 = {};
    {
      const unsigned short* kr0 = Kp + (size_t)(kv0 + l15) * 64 + lg * 8;
      const unsigned short* kr1 = Kp + (size_t)(kv0 + 16 + l15) * 64 + lg * 8;
      bf16x8 ka = *(const bf16x8*)kr0;
      bf16x8 kbv = *(const bf16x8*)(kr0 + 32);
      bf16x8 kc = *(const bf16x8*)kr1;
      bf16x8 kd = *(const bf16x8*)(kr1 + 32);
      st0 = MFMA16(ka, qf0, st0);
      st0 = MFMA16(kbv, qf1, st0);
      st1 = MFMA16(kc, qf0, st1);
      st1 = MFMA16(kd, qf1, st1);
    }
    // scale + causal mask + online softmax (log2 domain)
    float s[8];
    float mx = -1e30f;
#pragma unroll
    for (int fm = 0; fm < 2; ++fm)
#pragma unroll
      for (int r = 0; r < 4; ++r) {
        int key = kv0 + fm * 16 + lg * 4 + r;
        float v = (fm ? st1[r] : st0[r]) * sc;
        v = (key <= q_idx) ? v : -1e30f;
        s[fm * 4 + r] = v;
        mx = fmaxf(mx, v);
      }
    mx = fmaxf(mx, __shfl_xor(mx, 16));
    mx = fmaxf(mx, __shfl_xor(mx, 32));
    float m_new = fmaxf(m_run, mx);
    float alpha = exp2f(m_run - m_new);
    float ls = 0.f;
    unsigned short pb[8];
#pragma unroll
    for (int i = 0; i < 8; ++i) {
      float p = exp2f(s[i] - m_new);
      ls += p;
      pb[i] = f2b(p);
    }
    ls += __shfl_xor(ls, 16);
    ls += __shfl_xor(ls, 32);
    l_run = l_run * alpha + ls;
    m_run = m_new;
#pragma unroll
    for (int fd = 0; fd < 4; ++fd)
#pragma unroll
      for (int r = 0; r < 4; ++r) yacc[fd][r] *= alpha;

    // stage P^T (bf16) through per-wave LDS: layout [q(16)][48 pad], cols=key
    ushort4 w0, w1;
    w0.x = pb[0]; w0.y = pb[1]; w0.z = pb[2]; w0.w = pb[3];
    w1.x = pb[4]; w1.y = pb[5]; w1.z = pb[6]; w1.w = pb[7];
    *(ushort4*)&Pl[l15 * 48 + lg * 4] = w0;
    *(ushort4*)&Pl[l15 * 48 + 16 + lg * 4] = w1;
    bf16x8 pf = *(const bf16x8*)&Pl[l15 * 48 + lg * 8];

    // Y^T += V^T * P^T
#pragma unroll
    for (int fd = 0; fd < 4; ++fd) {
      bf16x8 vf = *(const bf16x8*)(Vt + (size_t)(fd * 16 + l15) * 2048 + kv0 + lg * 8);
      yacc[fd] = MFMA16(vf, pf, yacc[fd]);
    }
  }

  float inv = 1.f / l_run;
  int b = bh >> 4, h = bh & 15;
  size_t base = ((size_t)(b * 2048 + (q0 + l15)) * 16 + h) * 64;
#pragma unroll
  for (int fd = 0; fd < 4; ++fd)
#pragma unroll
    for (int r = 0; r < 4; ++r)
      y_att[base + fd * 16 + lg * 4 + r] = f2b(yacc[fd][r] * inv);
}

// ---------- launcher ----------
extern "C" void kernel_launch(void* const* d_in, const int* in_sizes, int n_in,
                              void* d_out, int out_size, void* d_ws, size_t ws_size,
                              hipStream_t stream) {
  const float* x = (const float*)d_in[0];
  const float* W_qkv = (const float*)d_in[1];
  const float* b_qkv = (const float*)d_in[2];
  const float* W_out = (const float*)d_in[3];
  const float* b_out = (const float*)d_in[4];

  float* y_out = (float*)d_out;                 // [2,2048,1024]
  float* k_out = y_out + 4194304;               // [2,16,2048,64]
  float* v_out = y_out + 8388608;               // [2,16,2048,64]

  unsigned short* x_bf = (unsigned short*)d_ws;       // [4096,1024]
  unsigned short* wqkv_t = x_bf + 4194304;            // [3072,1024]
  unsigned short* wout_t = wqkv_t + 3145728;          // [1024,1024]
  unsigned short* q_bf = wout_t + 1048576;            // [B,H,T,Dh]
  unsigned short* k_bf = q_bf + 4194304;              // [B,H,T,Dh]
  unsigned short* vt_bf = k_bf + 4194304;             // [B,H,Dh,T]
  unsigned short* y_att = vt_bf + 4194304;            // [B,T,H*Dh]

  conv_bf16_kernel<<<4096, 256, 0, stream>>>(x, x_bf, 4194304);
  transpose_bf16_kernel<<<dim3(96, 32), dim3(32, 32), 0, stream>>>(W_qkv, wqkv_t, 1024, 3072);
  transpose_bf16_kernel<<<dim3(32, 32), dim3(32, 32), 0, stream>>>(W_out, wout_t, 1024, 1024);
  gemm_bf16_kernel<0><<<dim3(24, 32), 256, 0, stream>>>(
      x_bf, wqkv_t, b_qkv, 4096, 3072, 1024, q_bf, k_bf, vt_bf, k_out, v_out, nullptr);
  attn_kernel<<<1024, 256, 0, stream>>>(q_bf, k_bf, vt_bf, y_att);
  gemm_bf16_kernel<1><<<dim3(8, 32), 256, 0, stream>>>(
      y_att, wout_t, b_out, 4096, 1024, 1024, nullptr, nullptr, nullptr, nullptr, nullptr, y_out);
}

// Round 2
// 167.113 us; speedup vs baseline: 1.3125x; 1.3125x over previous
//
#include <hip/hip_runtime.h>

// ---------- types ----------
typedef __attribute__((ext_vector_type(8))) short bf16x8;   // 8 bf16 = 4 VGPR
typedef __attribute__((ext_vector_type(4))) float f32x4;

#define MFMA16(A, B, C) __builtin_amdgcn_mfma_f32_16x16x32_bf16((A), (B), (C), 0, 0, 0)

// fp32 -> bf16 (round-to-nearest-even), header-independent
__device__ __forceinline__ unsigned short f2b(float f) {
  unsigned u = __builtin_bit_cast(unsigned, f);
  unsigned r = (u + 0x7fffu + ((u >> 16) & 1u)) >> 16;
  return (unsigned short)r;
}

// async global->LDS, 16B per lane. dest = wave-uniform base + lane*16
__device__ __forceinline__ void gload16(const void* g, void* l) {
  __builtin_amdgcn_global_load_lds(
      (const __attribute__((address_space(1))) void*)g,
      (__attribute__((address_space(3))) void*)l, 16, 0, 0);
}

// ---------- pre-pass: fp32 -> bf16 (vectorized) ----------
__global__ void conv_bf16_kernel(const float* __restrict__ src,
                                 unsigned short* __restrict__ dst, int n) {
  int i = (blockIdx.x * blockDim.x + threadIdx.x) * 4;
  if (i < n) {
    float4 v = *(const float4*)(src + i);
    ushort4 o;
    o.x = f2b(v.x); o.y = f2b(v.y); o.z = f2b(v.z); o.w = f2b(v.w);
    *(ushort4*)(dst + i) = o;
  }
}

// ---------- pre-pass: transpose fp32 [R][C] -> bf16 [C][R] ----------
__global__ __launch_bounds__(1024) void transpose_bf16_kernel(
    const float* __restrict__ src, unsigned short* __restrict__ dst, int R, int C) {
  __shared__ unsigned short t[32][33];
  int x = threadIdx.x, y = threadIdx.y;
  int c0 = blockIdx.x * 32, r0 = blockIdx.y * 32;
  t[y][x] = f2b(src[(size_t)(r0 + y) * C + c0 + x]);
  __syncthreads();
  dst[(size_t)(c0 + y) * R + r0 + x] = t[x][y];
}

// ---------- GEMM: C[M,N] = A[M,K] * Bt[N,K]^T (+bias), bf16 MFMA ----------
template <int MODE>
__global__ __launch_bounds__(256, 2) void gemm_bf16_kernel(
    const unsigned short* __restrict__ A, const unsigned short* __restrict__ Bt,
    const float* __restrict__ bias, int M, int N, int K,
    unsigned short* __restrict__ q_bf, unsigned short* __restrict__ k_bf,
    unsigned short* __restrict__ vt_bf, float* __restrict__ k_out,
    float* __restrict__ v_out, float* __restrict__ y_out) {
  __shared__ __align__(16) unsigned short As[128 * 64];
  __shared__ __align__(16) unsigned short Bs[128 * 64];
  const int tid = threadIdx.x;
  const int lane = tid & 63, wid = tid >> 6;
  const int wr = wid >> 1, wc = wid & 1;
  const int l15 = lane & 15, lg = lane >> 4;
  const int m0 = blockIdx.y * 128, n0 = blockIdx.x * 128;

  f32x4 acc[4][4] = {};

  int rowS[4], colS[4];
#pragma unroll
  for (int j = 0; j < 4; ++j) {
    int L = j * 4096 + wid * 1024 + lane * 16;  // linear LDS byte
    int row = L >> 7;
    int c = (L & 127) ^ ((row & 7) << 4);
    rowS[j] = row;
    colS[j] = c >> 1;  // bf16 elements
  }

  for (int kt = 0; kt < K; kt += 64) {
    __syncthreads();
#pragma unroll
    for (int j = 0; j < 4; ++j) {
      gload16(A + (size_t)(m0 + rowS[j]) * K + kt + colS[j],
              (char*)As + j * 4096 + wid * 1024);
      gload16(Bt + (size_t)(n0 + rowS[j]) * K + kt + colS[j],
              (char*)Bs + j * 4096 + wid * 1024);
    }
    __syncthreads();

    bf16x8 af[4][2], bfr[4][2];
#pragma unroll
    for (int i = 0; i < 4; ++i)
#pragma unroll
      for (int kk = 0; kk < 2; ++kk) {
        int ra = wr * 64 + i * 16 + l15;
        int cb = kk * 64 + lg * 16;
        af[i][kk] = *(const bf16x8*)((const char*)As + ra * 128 + (cb ^ ((ra & 7) << 4)));
        int rb = wc * 64 + i * 16 + l15;
        bfr[i][kk] = *(const bf16x8*)((const char*)Bs + rb * 128 + (cb ^ ((rb & 7) << 4)));
      }
#pragma unroll
    for (int mi = 0; mi < 4; ++mi)
#pragma unroll
      for (int ni = 0; ni < 4; ++ni)
#pragma unroll
        for (int kk = 0; kk < 2; ++kk)
          acc[mi][ni] = MFMA16(af[mi][kk], bfr[ni][kk], acc[mi][ni]);
  }

#pragma unroll
  for (int ni = 0; ni < 4; ++ni) {
    int gn = n0 + wc * 64 + ni * 16 + l15;
    float bv = bias[gn];
    if (MODE == 0) {
      int which = gn >> 10, rem = gn & 1023;
      int h = rem >> 6, dh = rem & 63;
#pragma unroll
      for (int mi = 0; mi < 4; ++mi) {
        int gmb = m0 + wr * 64 + mi * 16 + lg * 4;
#pragma unroll
        for (int r = 0; r < 4; ++r) {
          int gm = gmb + r;
          int b = gm >> 11, t = gm & 2047;
          float val = acc[mi][ni][r] + bv;
          size_t idx = ((size_t)((b * 16 + h) * 2048 + t)) * 64 + dh;
          if (which == 0) {
            q_bf[idx] = f2b(val);
          } else if (which == 1) {
            k_out[idx] = val;
            k_bf[idx] = f2b(val);
          } else {
            v_out[idx] = val;
            vt_bf[((size_t)(b * 16 + h) * 64 + dh) * 2048 + t] = f2b(val);
          }
        }
      }
    } else {
#pragma unroll
      for (int mi = 0; mi < 4; ++mi) {
        int gmb = m0 + wr * 64 + mi * 16 + lg * 4;
#pragma unroll
        for (int r = 0; r < 4; ++r)
          y_out[(size_t)(gmb + r) * N + gn] = acc[mi][ni][r] + bv;
      }
    }
  }
}

// ---------- causal flash attention ----------
// one wave per 32 q-rows (2 fragment groups); KV tiles of 32; swapped QK^T
// (S^T = K*Q^T) so q is lane-local. K[t+1] and V[t] prefetched at iteration
// top so no load latency sits on the MFMA/softmax critical path.
__global__ __launch_bounds__(256, 2) void attn_kernel(
    const unsigned short* __restrict__ qb, const unsigned short* __restrict__ kb,
    const unsigned short* __restrict__ vtb, unsigned short* __restrict__ y_att) {
  __shared__ __align__(16) unsigned short P_lds[4][32 * 40];
  const int tid = threadIdx.x, lane = tid & 63, w = tid >> 6;
  const int qt = 63 - (int)(blockIdx.x >> 3);      // heaviest tiles first
  const int bh = (int)((blockIdx.x & 7) << 2) | w; // 4 heads per block, same qt
  const int q0 = qt * 32;
  const int l15 = lane & 15, lg = lane >> 4;
  const size_t base_off = (size_t)bh * 2048 * 64;
  const unsigned short* Q = qb + base_off;
  const unsigned short* Kp = kb + base_off;
  const unsigned short* Vt = vtb + base_off;  // [64][2048]
  unsigned short* Pl = P_lds[w];

  bf16x8 qf[2][2];
#pragma unroll
  for (int qg = 0; qg < 2; ++qg)
#pragma unroll
    for (int ks = 0; ks < 2; ++ks)
      qf[qg][ks] = *(const bf16x8*)(Q + (size_t)(q0 + qg * 16 + l15) * 64 + ks * 32 + lg * 8);

  f32x4 yacc[2][4] = {};
  float m_run[2] = {-1e30f, -1e30f}, l_run[2] = {0.f, 0.f};
  const float sc = 0.125f * 1.44269504f;  // 1/sqrt(64) * log2(e)
  const int nt = qt + 1;

  // preload K tile 0
  bf16x8 kc[2][2];
#pragma unroll
  for (int kf = 0; kf < 2; ++kf)
#pragma unroll
    for (int ks = 0; ks < 2; ++ks)
      kc[kf][ks] = *(const bf16x8*)(Kp + (size_t)(kf * 16 + l15) * 64 + ks * 32 + lg * 8);

  for (int t = 0; t < nt; ++t) {
    const int kv0 = t * 32;
    // ---- prefetch: V[t] (needed after softmax), K[t+1] (needed next iter)
    bf16x8 vf[4];
#pragma unroll
    for (int fd = 0; fd < 4; ++fd)
      vf[fd] = *(const bf16x8*)(Vt + (size_t)(fd * 16 + l15) * 2048 + kv0 + lg * 8);
    const int kvn = (t + 1 < nt) ? kv0 + 32 : kv0;
    bf16x8 kn[2][2];
#pragma unroll
    for (int kf = 0; kf < 2; ++kf)
#pragma unroll
      for (int ks = 0; ks < 2; ++ks)
        kn[kf][ks] = *(const bf16x8*)(Kp + (size_t)(kvn + kf * 16 + l15) * 64 + ks * 32 + lg * 8);

    // ---- QK^T: S^T[key][q] for 32 keys x 32 q
    f32x4 st[2][2] = {};
#pragma unroll
    for (int qg = 0; qg < 2; ++qg)
#pragma unroll
      for (int kf = 0; kf < 2; ++kf) {
        st[qg][kf] = MFMA16(kc[kf][0], qf[qg][0], st[qg][kf]);
        st[qg][kf] = MFMA16(kc[kf][1], qf[qg][1], st[qg][kf]);
      }

    // ---- online softmax per q-group (log2 domain)
#pragma unroll
    for (int qg = 0; qg < 2; ++qg) {
      const int q_idx = q0 + qg * 16 + l15;
      float s[8];
      float mx = -1e30f;
#pragma unroll
      for (int kf = 0; kf < 2; ++kf)
#pragma unroll
        for (int r = 0; r < 4; ++r) {
          int key = kv0 + kf * 16 + lg * 4 + r;
          float v = st[qg][kf][r] * sc;
          v = (key <= q_idx) ? v : -1e30f;
          s[kf * 4 + r] = v;
          mx = fmaxf(mx, v);
        }
      mx = fmaxf(mx, __shfl_xor(mx, 16));
      mx = fmaxf(mx, __shfl_xor(mx, 32));
      float m_new = fmaxf(m_run[qg], mx);
      float alpha = exp2f(m_run[qg] - m_new);
      float ls = 0.f;
      unsigned short pb[8];
#pragma unroll
      for (int i = 0; i < 8; ++i) {
        float p = exp2f(s[i] - m_new);
        ls += p;
        pb[i] = f2b(p);
      }
      ls += __shfl_xor(ls, 16);
      ls += __shfl_xor(ls, 32);
      l_run[qg] = l_run[qg] * alpha + ls;
      m_run[qg] = m_new;
#pragma unroll
      for (int fd = 0; fd < 4; ++fd)
#pragma unroll
        for (int r = 0; r < 4; ++r) yacc[qg][fd][r] *= alpha;

      // stage P^T (bf16): [32 q][40 pad], cols = key-in-tile
      ushort4 w0, w1;
      w0.x = pb[0]; w0.y = pb[1]; w0.z = pb[2]; w0.w = pb[3];
      w1.x = pb[4]; w1.y = pb[5]; w1.z = pb[6]; w1.w = pb[7];
      *(ushort4*)&Pl[(qg * 16 + l15) * 40 + lg * 4] = w0;
      *(ushort4*)&Pl[(qg * 16 + l15) * 40 + 16 + lg * 4] = w1;
    }

    // ---- PV: Y^T += V^T * P^T
    bf16x8 pf[2];
#pragma unroll
    for (int qg = 0; qg < 2; ++qg)
      pf[qg] = *(const bf16x8*)&Pl[(qg * 16 + l15) * 40 + lg * 8];
#pragma unroll
    for (int qg = 0; qg < 2; ++qg)
#pragma unroll
      for (int fd = 0; fd < 4; ++fd)
        yacc[qg][fd] = MFMA16(vf[fd], pf[qg], yacc[qg][fd]);

#pragma unroll
    for (int kf = 0; kf < 2; ++kf)
#pragma unroll
      for (int ks = 0; ks < 2; ++ks) kc[kf][ks] = kn[kf][ks];
  }

  const int b = bh >> 4, h = bh & 15;
#pragma unroll
  for (int qg = 0; qg < 2; ++qg) {
    float inv = 1.f / l_run[qg];
    size_t base = ((size_t)(b * 2048 + (q0 + qg * 16 + l15)) * 16 + h) * 64;
#pragma unroll
    for (int fd = 0; fd < 4; ++fd)
#pragma unroll
      for (int r = 0; r < 4; ++r)
        y_att[base + fd * 16 + lg * 4 + r] = f2b(yacc[qg][fd][r] * inv);
  }
}

// ---------- launcher ----------
extern "C" void kernel_launch(void* const* d_in, const int* in_sizes, int n_in,
                              void* d_out, int out_size, void* d_ws, size_t ws_size,
                              hipStream_t stream) {
  const float* x = (const float*)d_in[0];
  const float* W_qkv = (const float*)d_in[1];
  const float* b_qkv = (const float*)d_in[2];
  const float* W_out = (const float*)d_in[3];
  const float* b_out = (const float*)d_in[4];

  float* y_out = (float*)d_out;                 // [2,2048,1024]
  float* k_out = y_out + 4194304;               // [2,16,2048,64]
  float* v_out = y_out + 8388608;               // [2,16,2048,64]

  unsigned short* x_bf = (unsigned short*)d_ws;       // [4096,1024]
  unsigned short* wqkv_t = x_bf + 4194304;            // [3072,1024]
  unsigned short* wout_t = wqkv_t + 3145728;          // [1024,1024]
  unsigned short* q_bf = wout_t + 1048576;            // [B,H,T,Dh]
  unsigned short* k_bf = q_bf + 4194304;              // [B,H,T,Dh]
  unsigned short* vt_bf = k_bf + 4194304;             // [B,H,Dh,T]
  unsigned short* y_att = vt_bf + 4194304;            // [B,T,H*Dh]

  conv_bf16_kernel<<<4096, 256, 0, stream>>>(x, x_bf, 4194304);
  transpose_bf16_kernel<<<dim3(96, 32), dim3(32, 32), 0, stream>>>(W_qkv, wqkv_t, 1024, 3072);
  transpose_bf16_kernel<<<dim3(32, 32), dim3(32, 32), 0, stream>>>(W_out, wout_t, 1024, 1024);
  gemm_bf16_kernel<0><<<dim3(24, 32), 256, 0, stream>>>(
      x_bf, wqkv_t, b_qkv, 4096, 3072, 1024, q_bf, k_bf, vt_bf, k_out, v_out, nullptr);
  attn_kernel<<<512, 256, 0, stream>>>(q_bf, k_bf, vt_bf, y_att);
  gemm_bf16_kernel<1><<<dim3(8, 32), 256, 0, stream>>>(
      y_att, wout_t, b_out, 4096, 1024, 1024, nullptr, nullptr, nullptr, nullptr, nullptr, y_out);
}